// Round 1
// baseline (285.470 us; speedup 1.0000x reference)
//
#include <hip/hip_runtime.h>
#include <hip/hip_bf16.h>

// TriMipEncoding: x[800000,3] f32, fm[3,512,512,16] f32 -> out[800000,48] f32
//
// R3 strategy: R2's gather showed FETCH ~= demand bytes (no over-fetch) and no
// saturated pipe (VALU 28%, HBM 52%, TA ~15%) => latency-bound with too little
// MLP (2-load stall, then 4-load stall per thread). This version fuses all 3
// planes into one thread: 12 independent texel loads issued back-to-back
// (3x queue depth), x read once per point (not 3x), magic-div by 3 eliminated
// (n = t>>3). Output stores stay perfectly coalesced (8 lanes = 64 B segment).

#define N_PTS 800000
#define PLANE 512
#define FDIM  16
#define FM_ELEMS (3 * PLANE * PLANE * FDIM)          // 12,582,912 floats
#define FMH_BYTES (FM_ELEMS * 2)                     // 25,165,824 B fp16
#define GATHER_THREADS (N_PTS * 8)                   // 6,400,000 (pt x chan-pair)
#define TOTAL_F32 (N_PTS * 48)                       // 38,400,000 (fallback)

typedef _Float16 half2v __attribute__((ext_vector_type(2)));
typedef _Float16 half4v __attribute__((ext_vector_type(4)));
typedef float    float2v __attribute__((ext_vector_type(2)));

__global__ __launch_bounds__(256) void convert_fp16_kernel(
    const float* __restrict__ fm, _Float16* __restrict__ fmh)
{
    unsigned t = blockIdx.x * blockDim.x + threadIdx.x;  // 3,145,728 threads
    float4 v = ((const float4*)fm)[t];
    half4v h;
    h.x = (_Float16)v.x; h.y = (_Float16)v.y;
    h.z = (_Float16)v.z; h.w = (_Float16)v.w;
    ((half4v*)fmh)[t] = h;
}

__global__ __launch_bounds__(256) void trimip_fp16_fused_kernel(
    const float* __restrict__ x,
    const _Float16* __restrict__ fmh,
    float* __restrict__ out)
{
    unsigned t = blockIdx.x * blockDim.x + threadIdx.x;
    if (t >= (unsigned)GATHER_THREADS) return;

    unsigned c2 = t & 7u;            // channel pair: channels {2*c2, 2*c2+1}
    unsigned n  = t >> 3;            // point index (no div-by-3 anymore)

    const float* xr = x + 3u * n;    // 8 lanes share n -> broadcast loads
    float x0 = __builtin_nontemporal_load(xr + 0);
    float x1 = __builtin_nontemporal_load(xr + 1);
    float x2 = __builtin_nontemporal_load(xr + 2);

    // plane p coords: p=0 -> (y,z); p=1 -> (x,z); p=2 -> (x,y)
    float ua[3] = {x1, x0, x0};
    float va[3] = {x2, x2, x1};

    float fu[3], fv[3];
    unsigned o00[3], o01[3], o10[3], o11[3];

#pragma unroll
    for (int p = 0; p < 3; ++p) {
        float u = ua[p] * (float)PLANE - 0.5f;
        float v = va[p] * (float)PLANE - 0.5f;
        float i0f = floorf(u);
        float j0f = floorf(v);
        fu[p] = u - i0f;
        fv[p] = v - j0f;

        int i0 = (int)i0f;
        int j0 = (int)j0f;
        int i1 = min(max(i0 + 1, 0), PLANE - 1);
        int j1 = min(max(j0 + 1, 0), PLANE - 1);
        i0 = min(max(i0, 0), PLANE - 1);
        j0 = min(max(j0, 0), PLANE - 1);

        unsigned pb = (unsigned)p * (PLANE * PLANE * FDIM) + 2u * c2;
        o00[p] = pb + (unsigned)(j0 * PLANE + i0) * FDIM;
        o01[p] = pb + (unsigned)(j0 * PLANE + i1) * FDIM;
        o10[p] = pb + (unsigned)(j1 * PLANE + i0) * FDIM;
        o11[p] = pb + (unsigned)(j1 * PLANE + i1) * FDIM;
    }

    // Issue all 12 texel loads before any use: 3x the in-flight requests of R2.
    half2v h00[3], h01[3], h10[3], h11[3];
#pragma unroll
    for (int p = 0; p < 3; ++p) {
        h00[p] = *(const half2v*)(fmh + o00[p]);
        h01[p] = *(const half2v*)(fmh + o01[p]);
        h10[p] = *(const half2v*)(fmh + o10[p]);
        h11[p] = *(const half2v*)(fmh + o11[p]);
    }

    // out row layout: [n][p][16 ch] -> float2 index n*24 + p*8 + c2
    float2v* ob = (float2v*)out + (size_t)n * 24u + c2;
#pragma unroll
    for (int p = 0; p < 3; ++p) {
        float2v r;
        {
            float t00 = (float)h00[p].x, t01 = (float)h01[p].x;
            float t10 = (float)h10[p].x, t11 = (float)h11[p].x;
            float r0 = t00 + fu[p] * (t01 - t00);
            float r1 = t10 + fu[p] * (t11 - t10);
            r.x = r0 + fv[p] * (r1 - r0);
        }
        {
            float t00 = (float)h00[p].y, t01 = (float)h01[p].y;
            float t10 = (float)h10[p].y, t11 = (float)h11[p].y;
            float r0 = t00 + fu[p] * (t01 - t00);
            float r1 = t10 + fu[p] * (t11 - t10);
            r.y = r0 + fv[p] * (r1 - r0);
        }
        __builtin_nontemporal_store(r, ob + (unsigned)p * 8u);
    }
}

// Fallback (proven R1 kernel) if ws_size can't hold the fp16 texture.
__global__ __launch_bounds__(256) void trimip_f32_kernel(
    const float* __restrict__ x,
    const float* __restrict__ fm,
    float* __restrict__ out)
{
    unsigned t = blockIdx.x * blockDim.x + threadIdx.x;
    if (t >= (unsigned)TOTAL_F32) return;

    unsigned c    = t & 15u;
    unsigned unit = t >> 4;
    unsigned n    = unit / 3u;
    unsigned p    = unit - n * 3u;

    unsigned iu = (p == 0u) ? 1u : 0u;
    unsigned iv = (p == 2u) ? 1u : 2u;

    float a = x[n * 3u + iu];
    float b = x[n * 3u + iv];

    float u = a * (float)PLANE - 0.5f;
    float v = b * (float)PLANE - 0.5f;
    float i0f = floorf(u);
    float j0f = floorf(v);
    float fu = u - i0f;
    float fv = v - j0f;

    int i0 = (int)i0f;
    int j0 = (int)j0f;
    int i1 = min(max(i0 + 1, 0), PLANE - 1);
    int j1 = min(max(j0 + 1, 0), PLANE - 1);
    i0 = min(max(i0, 0), PLANE - 1);
    j0 = min(max(j0, 0), PLANE - 1);

    const float* base = fm + (size_t)p * (PLANE * PLANE * FDIM);
    float t00 = base[((size_t)(j0 * PLANE + i0)) * FDIM + c];
    float t01 = base[((size_t)(j0 * PLANE + i1)) * FDIM + c];
    float t10 = base[((size_t)(j1 * PLANE + i0)) * FDIM + c];
    float t11 = base[((size_t)(j1 * PLANE + i1)) * FDIM + c];

    float r0 = t00 + fu * (t01 - t00);
    float r1 = t10 + fu * (t11 - t10);
    float r  = r0 + fv * (r1 - r0);

    __builtin_nontemporal_store(r, &out[t]);
}

extern "C" void kernel_launch(void* const* d_in, const int* in_sizes, int n_in,
                              void* d_out, int out_size, void* d_ws, size_t ws_size,
                              hipStream_t stream)
{
    const float* x  = (const float*)d_in[0];
    const float* fm = (const float*)d_in[1];
    float* out      = (float*)d_out;

    if (ws_size >= (size_t)FMH_BYTES) {
        _Float16* fmh = (_Float16*)d_ws;
        convert_fp16_kernel<<<FM_ELEMS / 4 / 256, 256, 0, stream>>>(fm, fmh);
        trimip_fp16_fused_kernel<<<(GATHER_THREADS + 255) / 256, 256, 0, stream>>>(x, fmh, out);
    } else {
        trimip_f32_kernel<<<(TOTAL_F32 + 255) / 256, 256, 0, stream>>>(x, fm, out);
    }
}